// Round 9
// baseline (375.489 us; speedup 1.0000x reference)
//
#include <hip/hip_runtime.h>
#include <hip/hip_bf16.h>
#include <math.h>

// Problem constants
#define B_  4
#define L_  512
#define H_  1024
#define M_  128
#define E_  64
#define NH_ 16
#define R_  1024
#define D_  768
#define BLK_ 64
#define C_  97
#define NROW (B_*R_)          // 4096
#define KB_  (D_/BLK_)        // 12

typedef __attribute__((ext_vector_type(8))) unsigned short ushort8;
typedef __attribute__((ext_vector_type(4))) unsigned short ushort4v;
typedef __attribute__((ext_vector_type(8))) short s8;       // 8 bf16 MFMA operand
typedef __attribute__((ext_vector_type(4))) float f4;       // MFMA C/D

__device__ __forceinline__ unsigned short f2bf(float x) {   // RNE f32->bf16
    unsigned u = __builtin_bit_cast(unsigned, x);
    unsigned r = (u + 0x7fffu + ((u >> 16) & 1u)) >> 16;
    return (unsigned short)r;
}
__device__ __forceinline__ float bf2f(unsigned short h) {
    unsigned u = ((unsigned)h) << 16;
    return __builtin_bit_cast(float, u);
}
__device__ __forceinline__ float lo16f(unsigned u) { return __builtin_bit_cast(float, u << 16); }
__device__ __forceinline__ float hi16f(unsigned u) { return __builtin_bit_cast(float, u & 0xffff0000u); }

// ===========================================================================
// Stage 1a: entity logsumexp pooling -> bf16 (R8-verified math, lse part only)
// ===========================================================================
__global__ __launch_bounds__(256) void pool_lse(
    const float* __restrict__ ent_lhs, const int* __restrict__ labels,
    unsigned short* __restrict__ ent_embB)
{
    int be = blockIdx.x, b = be >> 6, e = be & 63;
    __shared__ int midx[M_];
    __shared__ int scnt;
    if (threadIdx.x == 0) scnt = 0;
    __syncthreads();
    if (threadIdx.x < M_) {
        if (labels[b*M_ + threadIdx.x] == e) {
            int p = atomicAdd(&scnt, 1);
            midx[p] = threadIdx.x;
        }
    }
    __syncthreads();
    int cnt = scnt;
    for (int h = threadIdx.x; h < H_; h += blockDim.x) {
        float r = 0.f;
        if (cnt > 0) {
            const float* base = ent_lhs + (size_t)b*M_*H_ + h;
            float mx = -INFINITY;
            for (int k = 0; k < cnt; ++k) mx = fmaxf(mx, base[(size_t)midx[k]*H_]);
            float s = 0.f;
            for (int k = 0; k < cnt; ++k) s += expf(base[(size_t)midx[k]*H_] - mx);
            r = mx + logf(s);
        }
        ent_embB[(size_t)be*H_ + h] = f2bf(r);
    }
}

// ===========================================================================
// Stage 1b: entity attention mean -> bf16. grid (E, B*NH) = 4096 blocks
// (16x the parallelism of the fused R8 version; same coalesced traffic)
// ===========================================================================
__global__ __launch_bounds__(256) void pool_attn(
    const float* __restrict__ attn, const int* __restrict__ labels,
    unsigned short* __restrict__ ent_attnB)
{
    int e  = blockIdx.x;
    int y  = blockIdx.y;          // b*NH + nh
    int b  = y >> 4, nh = y & 15;
    __shared__ int midx[M_];
    __shared__ int scnt;
    if (threadIdx.x == 0) scnt = 0;
    __syncthreads();
    if (threadIdx.x < M_) {
        if (labels[b*M_ + threadIdx.x] == e) {
            int p = atomicAdd(&scnt, 1);
            midx[p] = threadIdx.x;
        }
    }
    __syncthreads();
    int cnt = scnt;
    float inv = (cnt > 0) ? 1.f/(float)cnt : 0.f;
    const float* base = attn + ((size_t)(b*NH_ + nh)*M_)*L_;
    #pragma unroll
    for (int q = 0; q < 2; ++q) {
        int l = threadIdx.x + q*256;
        float s = 0.f;
        for (int k = 0; k < cnt; ++k) s += base[(size_t)midx[k]*L_ + l];
        ent_attnB[((size_t)(b*E_ + e)*NH_ + nh)*L_ + l] = f2bf(s * inv);
    }
}

// ===========================================================================
// Stage 2: pair attention bf16 in -> bf16 htA (R8-verified)
// ===========================================================================
__global__ __launch_bounds__(256) void pair_attn_kernel(
    const unsigned short* __restrict__ entA, const int* __restrict__ hts,
    unsigned short* __restrict__ htA)
{
    int br = blockIdx.x, b = br >> 10;
    int hi = hts[br*2 + 0], ti = hts[br*2 + 1];
    const unsigned* ph = (const unsigned*)(entA + ((size_t)(b*E_ + hi)*NH_)*L_);
    const unsigned* pt = (const unsigned*)(entA + ((size_t)(b*E_ + ti)*NH_)*L_);
    int l2 = threadIdx.x;                 // u32 index = pair of adjacent l's
    float v0 = 0.f, v1 = 0.f;
    #pragma unroll
    for (int nh = 0; nh < NH_; ++nh) {
        unsigned a = ph[nh*(L_/2) + l2], c = pt[nh*(L_/2) + l2];
        v0 += lo16f(a)*lo16f(c);
        v1 += hi16f(a)*hi16f(c);
    }
    float part = v0 + v1;
    __shared__ float red[4];
    #pragma unroll
    for (int off = 32; off > 0; off >>= 1) part += __shfl_down(part, off, 64);
    if ((threadIdx.x & 63) == 0) red[threadIdx.x >> 6] = part;
    __syncthreads();
    float total = red[0] + red[1] + red[2] + red[3];
    float norm = 1.f / (total*(1.f/16.f) + 1e-5f);   // denom on sum of nh-means
    unsigned short o0 = f2bf(v0*(1.f/16.f)*norm);
    unsigned short o1 = f2bf(v1*(1.f/16.f)*norm);
    *(unsigned*)(htA + (size_t)br*L_ + l2*2) = ((unsigned)o1 << 16) | o0;
}

// ===========================================================================
// Preps (R8-verified)
// ===========================================================================
__global__ __launch_bounds__(256) void transpose_cvt_seq(const float* __restrict__ in,
                                                         unsigned short* __restrict__ outp)
{
    int b = blockIdx.z;
    int h0 = blockIdx.x*32, l0 = blockIdx.y*32;
    __shared__ float tile[32][33];
    int tx = threadIdx.x & 31, ty = threadIdx.x >> 5;
    #pragma unroll
    for (int p = 0; p < 4; ++p)
        tile[ty + p*8][tx] = in[((size_t)b*L_ + l0 + ty + p*8)*H_ + h0 + tx];
    __syncthreads();
    #pragma unroll
    for (int p = 0; p < 4; ++p)
        outp[((size_t)b*H_ + h0 + ty + p*8)*L_ + l0 + tx] = f2bf(tile[tx][ty + p*8]);
}

__global__ __launch_bounds__(256) void transpose_cvt_W(const float* __restrict__ Wh,
                                                       const float* __restrict__ Wt,
                                                       unsigned short* __restrict__ WhT,
                                                       unsigned short* __restrict__ WtT)
{
    const float* in = blockIdx.z ? Wt : Wh;
    unsigned short* outp = blockIdx.z ? WtT : WhT;
    int n0 = blockIdx.x*32, k0 = blockIdx.y*32;
    __shared__ float tile[32][33];
    int tx = threadIdx.x & 31, ty = threadIdx.x >> 5;
    #pragma unroll
    for (int p = 0; p < 4; ++p)
        tile[ty + p*8][tx] = in[((size_t)(k0 + ty + p*8))*D_ + n0 + tx];
    __syncthreads();
    #pragma unroll
    for (int p = 0; p < 4; ++p) {
        int n = n0 + ty + p*8;
        outp[(size_t)n*2048 + k0 + tx] = f2bf(tile[tx][ty + p*8]);
    }
}

// gather ent rows (bf16 copy) into Ah/At cols [0,1024)  (R8-verified)
__global__ __launch_bounds__(256) void prep_gather(const unsigned short* __restrict__ entE,
                                                   const int* __restrict__ hts,
                                                   unsigned short* __restrict__ Ah,
                                                   unsigned short* __restrict__ At)
{
    int n = blockIdx.x, b = n >> 10;
    int m = threadIdx.x >> 7, off = (threadIdx.x & 127)*8;
    int idx = hts[n*2 + m];
    const unsigned short* src = entE + (size_t)(b*E_ + idx)*H_ + off;
    unsigned short* dst = (m ? At : Ah) + (size_t)n*2048 + off;
    *(ushort8*)dst = *(const ushort8*)src;
}

__global__ __launch_bounds__(256) void prep_WbT(const float* __restrict__ Wb,
                                                unsigned short* __restrict__ outp)
{
    int blk = blockIdx.x;                 // kb*64 + i
    __shared__ float sW[64*97];
    const float* src = Wb + (size_t)blk*64*97;
    for (int e = threadIdx.x; e < 64*97; e += 256) sW[e] = src[e];
    __syncthreads();
    unsigned short* dst = outp + (size_t)blk*128*64;
    for (int e = threadIdx.x; e < 128*64; e += 256) {
        int c = e >> 6, j = e & 63;
        dst[e] = (c < C_) ? f2bf(sW[j*97 + c]) : (unsigned short)0;
    }
}

// ===========================================================================
// bf16 MFMA GEMM core (R8-verified)
// ===========================================================================
__device__ __forceinline__ void gemm128_core(const unsigned short* __restrict__ A,
                                             const unsigned short* __restrict__ Bt,
                                             int K, int row0, int col0,
                                             f4 (&acc)[4][4])
{
    __shared__ __attribute__((aligned(16))) unsigned short As[128][40];
    __shared__ __attribute__((aligned(16))) unsigned short Bs[128][40];
    int tid = threadIdx.x;
    int wave = tid >> 6, lane = tid & 63;
    int wr = wave & 1, wc = wave >> 1;
    int lm = lane & 15, quad = lane >> 4;

    for (int k0 = 0; k0 < K; k0 += 32) {
        #pragma unroll
        for (int s = 0; s < 2; ++s) {
            int ch = tid + s*256;
            int row = ch >> 2, part = ch & 3;
            *(ushort8*)&As[row][part*8] = *(const ushort8*)(A + (size_t)(row0 + row)*K + k0 + part*8);
            *(ushort8*)&Bs[row][part*8] = *(const ushort8*)(Bt + (size_t)(col0 + row)*K + k0 + part*8);
        }
        __syncthreads();
        s8 a[4], b[4];
        #pragma unroll
        for (int ti = 0; ti < 4; ++ti) a[ti] = *(const s8*)&As[wr*64 + ti*16 + lm][quad*8];
        #pragma unroll
        for (int tj = 0; tj < 4; ++tj) b[tj] = *(const s8*)&Bs[wc*64 + tj*16 + lm][quad*8];
        #pragma unroll
        for (int ti = 0; ti < 4; ++ti)
            #pragma unroll
            for (int tj = 0; tj < 4; ++tj)
                acc[ti][tj] = __builtin_amdgcn_mfma_f32_16x16x32_bf16(a[ti], b[tj], acc[ti][tj], 0, 0, 0);
        __syncthreads();
    }
}

// ===========================================================================
// Stage 3: rel GEMM -> bf16 into Ah/At cols [1024,2048)  (R8-verified)
// ===========================================================================
__global__ __launch_bounds__(256) void gemm_rel_mfma(const unsigned short* __restrict__ htA,
                                                     const unsigned short* __restrict__ seqT,
                                                     unsigned short* __restrict__ Ah,
                                                     unsigned short* __restrict__ At)
{
    int z = blockIdx.z;
    const unsigned short* A  = htA  + (size_t)z*R_*L_;
    const unsigned short* Bt = seqT + (size_t)z*H_*L_;
    int row0 = blockIdx.y*128, col0 = blockIdx.x*128;
    f4 acc[4][4] = {};
    gemm128_core(A, Bt, L_, row0, col0, acc);
    int lane = threadIdx.x & 63, wave = threadIdx.x >> 6;
    int wr = wave & 1, wc = wave >> 1, lm = lane & 15, quad = lane >> 4;
    #pragma unroll
    for (int ti = 0; ti < 4; ++ti)
        #pragma unroll
        for (int tj = 0; tj < 4; ++tj)
            #pragma unroll
            for (int r = 0; r < 4; ++r) {
                int n   = z*R_ + row0 + wr*64 + ti*16 + quad*4 + r;
                int col = col0 + wc*64 + tj*16 + lm;
                unsigned short v = f2bf(acc[ti][tj][r]);
                Ah[(size_t)n*2048 + 1024 + col] = v;
                At[(size_t)n*2048 + 1024 + col] = v;
            }
}

// ===========================================================================
// Stage 4: extractor GEMM (R8-verified, K=2048) + bias + tanh -> f32 hv/tv
// ===========================================================================
__global__ __launch_bounds__(256) void gemm_ext_mfma(
    const unsigned short* __restrict__ Ah, const unsigned short* __restrict__ At,
    const unsigned short* __restrict__ WhT, const unsigned short* __restrict__ WtT,
    const float* __restrict__ bh, const float* __restrict__ bt,
    float* __restrict__ hv, float* __restrict__ tv)
{
    int z = blockIdx.z;
    const unsigned short* A  = z ? At  : Ah;
    const unsigned short* Bt = z ? WtT : WhT;
    const float* bias = z ? bt : bh;
    float* C = z ? tv : hv;
    int row0 = blockIdx.y*128, col0 = blockIdx.x*128;
    f4 acc[4][4] = {};
    gemm128_core(A, Bt, 2048, row0, col0, acc);
    int lane = threadIdx.x & 63, wave = threadIdx.x >> 6;
    int wr = wave & 1, wc = wave >> 1, lm = lane & 15, quad = lane >> 4;
    #pragma unroll
    for (int ti = 0; ti < 4; ++ti)
        #pragma unroll
        for (int tj = 0; tj < 4; ++tj)
            #pragma unroll
            for (int r = 0; r < 4; ++r) {
                int row = row0 + wr*64 + ti*16 + quad*4 + r;
                int col = col0 + wc*64 + tj*16 + lm;
                float x = acc[ti][tj][r] + bias[col];
                float e = __expf(2.f*x);
                C[(size_t)row*D_ + col] = 1.f - 2.f/(e + 1.f);   // tanh
            }
}

// ===========================================================================
// Stage 5a: init output with bias
// ===========================================================================
__global__ void out_init(const float* __restrict__ bb, float* __restrict__ out)
{
    int i = blockIdx.x*256 + threadIdx.x;
    if (i < NROW*C_) out[i] = bb[i % C_];
}

// ===========================================================================
// Stage 5b: block-bilinear classifier — R8-verified scalar compute path +
// bf16 LDS + register-prefetch Ws; ONE change: 128 rows/block (wr*64, rt<4,
// acc[4][4]) to HALVE aggregate Ws streaming (768 -> 384 MB).
// grid (32 rowtiles, 12 kb). LDS = 2*128*72*2 + 32768 = 69632 B -> 2 blk/CU.
// ===========================================================================
__global__ __launch_bounds__(256) void final_mfma(
    const float* __restrict__ hv,             // [4096][768] f32
    const float* __restrict__ tv,
    const unsigned short* __restrict__ WbT,   // [12][64][128][64] bf16
    float* __restrict__ out)                  // [4096][97] f32
{
    int row0 = blockIdx.x * 128;
    int kb   = blockIdx.y;
    __shared__ __attribute__((aligned(16))) unsigned short hS[128][72];
    __shared__ __attribute__((aligned(16))) unsigned short tS[128][72];
    __shared__ __attribute__((aligned(16))) unsigned short Ws[2][128*64];

    int tid = threadIdx.x;
    // stage hv/tv kb-slices (128 rows x 64), f32 -> bf16 on the fly
    for (int e = tid; e < 2048; e += 256) {
        int r = e >> 4, part = e & 15;
        float4 xh = *(const float4*)(hv + (size_t)(row0 + r)*D_ + kb*BLK_ + part*4);
        float4 xt = *(const float4*)(tv + (size_t)(row0 + r)*D_ + kb*BLK_ + part*4);
        ushort4v ph = { f2bf(xh.x), f2bf(xh.y), f2bf(xh.z), f2bf(xh.w) };
        ushort4v pt = { f2bf(xt.x), f2bf(xt.y), f2bf(xt.z), f2bf(xt.w) };
        *(ushort4v*)&hS[r][part*4] = ph;
        *(ushort4v*)&tS[r][part*4] = pt;
    }
    int wave = tid >> 6, lane = tid & 63;
    int wr = wave & 1, wc = wave >> 1;
    int lm = lane & 15, quad = lane >> 4;
    __syncthreads();

    // preload tv fragments as scalar f32 (i-invariant within this kb)
    float tvv[4][2][8];   // [rowtile][jhalf][t]
    #pragma unroll
    for (int rt = 0; rt < 4; ++rt)
        #pragma unroll
        for (int j2 = 0; j2 < 2; ++j2) {
            int r = wr*64 + rt*16 + lm;
            ushort8 w = *(const ushort8*)&tS[r][j2*32 + quad*8];
            #pragma unroll
            for (int t = 0; t < 8; ++t) tvv[rt][j2][t] = bf2f(w[t]);
        }

    f4 acc[4][4] = {};
    const unsigned short* wbase = WbT + (size_t)kb*64*128*64;

    // precompute per-thread staging indices (R8-verified mapping)
    int swz_off[8];
    #pragma unroll
    for (int s = 0; s < 8; ++s) {
        int ch = tid + s*256;
        int ip = ch >> 10, rem = ch & 1023, c = rem >> 3, g = rem & 7;
        swz_off[s] = ip*(128*64) + c*64 + ((g ^ (c & 7))*8);
    }

    for (int i0 = 0; i0 < 64; i0 += 2) {
        // 8 independent loads first — latency overlaps previous iter's MFMAs
        ushort8 vbuf[8];
        #pragma unroll
        for (int s = 0; s < 8; ++s) {
            int ch = tid + s*256;
            int ip = ch >> 10, rem = ch & 1023, c = rem >> 3, g = rem & 7;
            vbuf[s] = *(const ushort8*)(wbase + (size_t)((i0 + ip)*128 + c)*64 + g*8);
        }
        __syncthreads();   // previous iteration's compute done; Ws reusable
        #pragma unroll
        for (int s = 0; s < 8; ++s)
            *(ushort8*)&Ws[0][swz_off[s]] = vbuf[s];
        __syncthreads();

        #pragma unroll
        for (int ip = 0; ip < 2; ++ip) {
            int i = i0 + ip;
            float shv[4];
            #pragma unroll
            for (int rt = 0; rt < 4; ++rt)
                shv[rt] = bf2f(hS[wr*64 + rt*16 + lm][i]);
            #pragma unroll
            for (int j2 = 0; j2 < 2; ++j2) {
                // build A-frags: bf16-truncate(sh * tvv) packed via v_perm
                s8 afr[4];
                #pragma unroll
                for (int rt = 0; rt < 4; ++rt) {
                    float sh = shv[rt];
                    union { unsigned u[4]; s8 v; } cv;
                    #pragma unroll
                    for (int t2 = 0; t2 < 4; ++t2) {
                        float pe = sh * tvv[rt][j2][t2*2];
                        float po = sh * tvv[rt][j2][t2*2 + 1];
                        cv.u[t2] = __builtin_amdgcn_perm(__builtin_bit_cast(unsigned, po),
                                                         __builtin_bit_cast(unsigned, pe),
                                                         0x07060302u);
                    }
                    afr[rt] = cv.v;
                }
                #pragma unroll
                for (int ct = 0; ct < 4; ++ct) {
                    int c = wc*64 + ct*16 + lm;
                    int g = j2*4 + quad;
                    s8 bfr = *(const s8*)&Ws[ip][c*64 + ((g ^ (c & 7))*8)];
                    #pragma unroll
                    for (int rt = 0; rt < 4; ++rt)
                        acc[rt][ct] = __builtin_amdgcn_mfma_f32_16x16x32_bf16(afr[rt], bfr, acc[rt][ct], 0, 0, 0);
                }
            }
        }
    }

    #pragma unroll
    for (int rt = 0; rt < 4; ++rt)
        #pragma unroll
        for (int ct = 0; ct < 4; ++ct)
            #pragma unroll
            for (int r = 0; r < 4; ++r) {
                int row = row0 + wr*64 + rt*16 + quad*4 + r;
                int col = wc*64 + ct*16 + lm;
                if (col < C_) atomicAdd(out + (size_t)row*C_ + col, acc[rt][ct][r]);
            }
}

// ===========================================================================
extern "C" void kernel_launch(void* const* d_in, const int* in_sizes, int n_in,
                              void* d_out, int out_size, void* d_ws, size_t ws_size,
                              hipStream_t stream)
{
    const float* seq_lhs = (const float*)d_in[0];
    const float* ent_lhs = (const float*)d_in[1];
    const float* attn    = (const float*)d_in[2];
    const int*   labels  = (const int*)d_in[3];
    const int*   hts     = (const int*)d_in[4];
    const float* Wh      = (const float*)d_in[5];
    const float* bh      = (const float*)d_in[6];
    const float* Wt      = (const float*)d_in[7];
    const float* bt      = (const float*)d_in[8];
    const float* Wb      = (const float*)d_in[9];
    const float* bb      = (const float*)d_in[10];
    float* out = (float*)d_out;

    float* wsf      = (float*)d_ws;
    float* hv       = wsf;                       // 3145728 f32
    float* tv       = hv + 3145728;              // 3145728 f32
    unsigned short* ent_embB  = (unsigned short*)(tv + 3145728); // 262144
    unsigned short* ent_attnB = ent_embB  + 262144;   // 2097152
    unsigned short* htA       = ent_attnB + 2097152;  // 2097152
    unsigned short* seqT      = htA       + 2097152;  // 2097152
    unsigned short* WhT       = seqT      + 2097152;  // 1572864
    unsigned short* WtT       = WhT       + 1572864;  // 1572864
    unsigned short* Ah        = WtT       + 1572864;  // 8388608 ([4096][2048])
    unsigned short* At        = Ah        + 8388608;  // 8388608
    unsigned short* WbT       = At        + 8388608;  // 6291456
    // total ~90.4 MB

    // weight preps (independent of activations)
    transpose_cvt_W<<<dim3(24, 64, 2), 256, 0, stream>>>(Wh, Wt, WhT, WtT);
    prep_WbT<<<KB_*64, 256, 0, stream>>>(Wb, WbT);
    transpose_cvt_seq<<<dim3(32, 16, B_), 256, 0, stream>>>(seq_lhs, seqT);

    pool_lse<<<B_*E_, 256, 0, stream>>>(ent_lhs, labels, ent_embB);
    pool_attn<<<dim3(E_, B_*NH_), 256, 0, stream>>>(attn, labels, ent_attnB);
    pair_attn_kernel<<<B_*R_, 256, 0, stream>>>(ent_attnB, hts, htA);
    gemm_rel_mfma<<<dim3(8, 8, B_), 256, 0, stream>>>(htA, seqT, Ah, At);
    prep_gather<<<NROW, 256, 0, stream>>>(ent_embB, hts, Ah, At);
    gemm_ext_mfma<<<dim3(6, 32, 2), 256, 0, stream>>>(Ah, At, WhT, WtT, bh, bt, hv, tv);
    out_init<<<(NROW*C_ + 255)/256, 256, 0, stream>>>(bb, out);
    final_mfma<<<dim3(NROW/128, KB_), 256, 0, stream>>>(hv, tv, WbT, out);
}

// Round 10
// 314.062 us; speedup vs baseline: 1.1956x; 1.1956x over previous
//
#include <hip/hip_runtime.h>
#include <hip/hip_bf16.h>
#include <math.h>

// Problem constants
#define B_  4
#define L_  512
#define H_  1024
#define M_  128
#define E_  64
#define NH_ 16
#define R_  1024
#define D_  768
#define BLK_ 64
#define C_  97
#define NROW (B_*R_)          // 4096
#define KB_  (D_/BLK_)        // 12

typedef __attribute__((ext_vector_type(8))) unsigned short ushort8;
typedef __attribute__((ext_vector_type(4))) unsigned short ushort4v;
typedef __attribute__((ext_vector_type(8))) short s8;       // 8 bf16 MFMA operand
typedef __attribute__((ext_vector_type(4))) float f4;       // MFMA C/D

__device__ __forceinline__ unsigned short f2bf(float x) {   // RNE f32->bf16
    unsigned u = __builtin_bit_cast(unsigned, x);
    unsigned r = (u + 0x7fffu + ((u >> 16) & 1u)) >> 16;
    return (unsigned short)r;
}
__device__ __forceinline__ float bf2f(unsigned short h) {
    unsigned u = ((unsigned)h) << 16;
    return __builtin_bit_cast(float, u);
}
__device__ __forceinline__ float lo16f(unsigned u) { return __builtin_bit_cast(float, u << 16); }
__device__ __forceinline__ float hi16f(unsigned u) { return __builtin_bit_cast(float, u & 0xffff0000u); }

// ===========================================================================
// Stage 1a: entity logsumexp pooling -> bf16 (R9-verified)
// ===========================================================================
__global__ __launch_bounds__(256) void pool_lse(
    const float* __restrict__ ent_lhs, const int* __restrict__ labels,
    unsigned short* __restrict__ ent_embB)
{
    int be = blockIdx.x, b = be >> 6, e = be & 63;
    __shared__ int midx[M_];
    __shared__ int scnt;
    if (threadIdx.x == 0) scnt = 0;
    __syncthreads();
    if (threadIdx.x < M_) {
        if (labels[b*M_ + threadIdx.x] == e) {
            int p = atomicAdd(&scnt, 1);
            midx[p] = threadIdx.x;
        }
    }
    __syncthreads();
    int cnt = scnt;
    for (int h = threadIdx.x; h < H_; h += blockDim.x) {
        float r = 0.f;
        if (cnt > 0) {
            const float* base = ent_lhs + (size_t)b*M_*H_ + h;
            float mx = -INFINITY;
            for (int k = 0; k < cnt; ++k) mx = fmaxf(mx, base[(size_t)midx[k]*H_]);
            float s = 0.f;
            for (int k = 0; k < cnt; ++k) s += expf(base[(size_t)midx[k]*H_] - mx);
            r = mx + logf(s);
        }
        ent_embB[(size_t)be*H_ + h] = f2bf(r);
    }
}

// ===========================================================================
// Stage 1b: entity attention mean -> bf16. grid (E, B*NH)  (R9-verified)
// ===========================================================================
__global__ __launch_bounds__(256) void pool_attn(
    const float* __restrict__ attn, const int* __restrict__ labels,
    unsigned short* __restrict__ ent_attnB)
{
    int e  = blockIdx.x;
    int y  = blockIdx.y;          // b*NH + nh
    int b  = y >> 4, nh = y & 15;
    __shared__ int midx[M_];
    __shared__ int scnt;
    if (threadIdx.x == 0) scnt = 0;
    __syncthreads();
    if (threadIdx.x < M_) {
        if (labels[b*M_ + threadIdx.x] == e) {
            int p = atomicAdd(&scnt, 1);
            midx[p] = threadIdx.x;
        }
    }
    __syncthreads();
    int cnt = scnt;
    float inv = (cnt > 0) ? 1.f/(float)cnt : 0.f;
    const float* base = attn + ((size_t)(b*NH_ + nh)*M_)*L_;
    #pragma unroll
    for (int q = 0; q < 2; ++q) {
        int l = threadIdx.x + q*256;
        float s = 0.f;
        for (int k = 0; k < cnt; ++k) s += base[(size_t)midx[k]*L_ + l];
        ent_attnB[((size_t)(b*E_ + e)*NH_ + nh)*L_ + l] = f2bf(s * inv);
    }
}

// ===========================================================================
// Stage 2: pair attention bf16 in -> bf16 htA (R8-verified)
// ===========================================================================
__global__ __launch_bounds__(256) void pair_attn_kernel(
    const unsigned short* __restrict__ entA, const int* __restrict__ hts,
    unsigned short* __restrict__ htA)
{
    int br = blockIdx.x, b = br >> 10;
    int hi = hts[br*2 + 0], ti = hts[br*2 + 1];
    const unsigned* ph = (const unsigned*)(entA + ((size_t)(b*E_ + hi)*NH_)*L_);
    const unsigned* pt = (const unsigned*)(entA + ((size_t)(b*E_ + ti)*NH_)*L_);
    int l2 = threadIdx.x;                 // u32 index = pair of adjacent l's
    float v0 = 0.f, v1 = 0.f;
    #pragma unroll
    for (int nh = 0; nh < NH_; ++nh) {
        unsigned a = ph[nh*(L_/2) + l2], c = pt[nh*(L_/2) + l2];
        v0 += lo16f(a)*lo16f(c);
        v1 += hi16f(a)*hi16f(c);
    }
    float part = v0 + v1;
    __shared__ float red[4];
    #pragma unroll
    for (int off = 32; off > 0; off >>= 1) part += __shfl_down(part, off, 64);
    if ((threadIdx.x & 63) == 0) red[threadIdx.x >> 6] = part;
    __syncthreads();
    float total = red[0] + red[1] + red[2] + red[3];
    float norm = 1.f / (total*(1.f/16.f) + 1e-5f);   // denom on sum of nh-means
    unsigned short o0 = f2bf(v0*(1.f/16.f)*norm);
    unsigned short o1 = f2bf(v1*(1.f/16.f)*norm);
    *(unsigned*)(htA + (size_t)br*L_ + l2*2) = ((unsigned)o1 << 16) | o0;
}

// ===========================================================================
// Preps (R8-verified)
// ===========================================================================
__global__ __launch_bounds__(256) void transpose_cvt_seq(const float* __restrict__ in,
                                                         unsigned short* __restrict__ outp)
{
    int b = blockIdx.z;
    int h0 = blockIdx.x*32, l0 = blockIdx.y*32;
    __shared__ float tile[32][33];
    int tx = threadIdx.x & 31, ty = threadIdx.x >> 5;
    #pragma unroll
    for (int p = 0; p < 4; ++p)
        tile[ty + p*8][tx] = in[((size_t)b*L_ + l0 + ty + p*8)*H_ + h0 + tx];
    __syncthreads();
    #pragma unroll
    for (int p = 0; p < 4; ++p)
        outp[((size_t)b*H_ + h0 + ty + p*8)*L_ + l0 + tx] = f2bf(tile[tx][ty + p*8]);
}

__global__ __launch_bounds__(256) void transpose_cvt_W(const float* __restrict__ Wh,
                                                       const float* __restrict__ Wt,
                                                       unsigned short* __restrict__ WhT,
                                                       unsigned short* __restrict__ WtT)
{
    const float* in = blockIdx.z ? Wt : Wh;
    unsigned short* outp = blockIdx.z ? WtT : WhT;
    int n0 = blockIdx.x*32, k0 = blockIdx.y*32;
    __shared__ float tile[32][33];
    int tx = threadIdx.x & 31, ty = threadIdx.x >> 5;
    #pragma unroll
    for (int p = 0; p < 4; ++p)
        tile[ty + p*8][tx] = in[((size_t)(k0 + ty + p*8))*D_ + n0 + tx];
    __syncthreads();
    #pragma unroll
    for (int p = 0; p < 4; ++p) {
        int n = n0 + ty + p*8;
        outp[(size_t)n*2048 + k0 + tx] = f2bf(tile[tx][ty + p*8]);
    }
}

// gather ent rows (bf16 copy) into Ah/At cols [0,1024)  (R8-verified)
__global__ __launch_bounds__(256) void prep_gather(const unsigned short* __restrict__ entE,
                                                   const int* __restrict__ hts,
                                                   unsigned short* __restrict__ Ah,
                                                   unsigned short* __restrict__ At)
{
    int n = blockIdx.x, b = n >> 10;
    int m = threadIdx.x >> 7, off = (threadIdx.x & 127)*8;
    int idx = hts[n*2 + m];
    const unsigned short* src = entE + (size_t)(b*E_ + idx)*H_ + off;
    unsigned short* dst = (m ? At : Ah) + (size_t)n*2048 + off;
    *(ushort8*)dst = *(const ushort8*)src;
}

__global__ __launch_bounds__(256) void prep_WbT(const float* __restrict__ Wb,
                                                unsigned short* __restrict__ outp)
{
    int blk = blockIdx.x;                 // kb*64 + i
    __shared__ float sW[64*97];
    const float* src = Wb + (size_t)blk*64*97;
    for (int e = threadIdx.x; e < 64*97; e += 256) sW[e] = src[e];
    __syncthreads();
    unsigned short* dst = outp + (size_t)blk*128*64;
    for (int e = threadIdx.x; e < 128*64; e += 256) {
        int c = e >> 6, j = e & 63;
        dst[e] = (c < C_) ? f2bf(sW[j*97 + c]) : (unsigned short)0;
    }
}

// ===========================================================================
// bf16 MFMA GEMM core (R8-verified)
// ===========================================================================
__device__ __forceinline__ void gemm128_core(const unsigned short* __restrict__ A,
                                             const unsigned short* __restrict__ Bt,
                                             int K, int row0, int col0,
                                             f4 (&acc)[4][4])
{
    __shared__ __attribute__((aligned(16))) unsigned short As[128][40];
    __shared__ __attribute__((aligned(16))) unsigned short Bs[128][40];
    int tid = threadIdx.x;
    int wave = tid >> 6, lane = tid & 63;
    int wr = wave & 1, wc = wave >> 1;
    int lm = lane & 15, quad = lane >> 4;

    for (int k0 = 0; k0 < K; k0 += 32) {
        #pragma unroll
        for (int s = 0; s < 2; ++s) {
            int ch = tid + s*256;
            int row = ch >> 2, part = ch & 3;
            *(ushort8*)&As[row][part*8] = *(const ushort8*)(A + (size_t)(row0 + row)*K + k0 + part*8);
            *(ushort8*)&Bs[row][part*8] = *(const ushort8*)(Bt + (size_t)(col0 + row)*K + k0 + part*8);
        }
        __syncthreads();
        s8 a[4], b[4];
        #pragma unroll
        for (int ti = 0; ti < 4; ++ti) a[ti] = *(const s8*)&As[wr*64 + ti*16 + lm][quad*8];
        #pragma unroll
        for (int tj = 0; tj < 4; ++tj) b[tj] = *(const s8*)&Bs[wc*64 + tj*16 + lm][quad*8];
        #pragma unroll
        for (int ti = 0; ti < 4; ++ti)
            #pragma unroll
            for (int tj = 0; tj < 4; ++tj)
                acc[ti][tj] = __builtin_amdgcn_mfma_f32_16x16x32_bf16(a[ti], b[tj], acc[ti][tj], 0, 0, 0);
        __syncthreads();
    }
}

// ===========================================================================
// Stage 3: rel GEMM -> bf16 into Ah/At cols [1024,2048)  (R8-verified)
// ===========================================================================
__global__ __launch_bounds__(256) void gemm_rel_mfma(const unsigned short* __restrict__ htA,
                                                     const unsigned short* __restrict__ seqT,
                                                     unsigned short* __restrict__ Ah,
                                                     unsigned short* __restrict__ At)
{
    int z = blockIdx.z;
    const unsigned short* A  = htA  + (size_t)z*R_*L_;
    const unsigned short* Bt = seqT + (size_t)z*H_*L_;
    int row0 = blockIdx.y*128, col0 = blockIdx.x*128;
    f4 acc[4][4] = {};
    gemm128_core(A, Bt, L_, row0, col0, acc);
    int lane = threadIdx.x & 63, wave = threadIdx.x >> 6;
    int wr = wave & 1, wc = wave >> 1, lm = lane & 15, quad = lane >> 4;
    #pragma unroll
    for (int ti = 0; ti < 4; ++ti)
        #pragma unroll
        for (int tj = 0; tj < 4; ++tj)
            #pragma unroll
            for (int r = 0; r < 4; ++r) {
                int n   = z*R_ + row0 + wr*64 + ti*16 + quad*4 + r;
                int col = col0 + wc*64 + tj*16 + lm;
                unsigned short v = f2bf(acc[ti][tj][r]);
                Ah[(size_t)n*2048 + 1024 + col] = v;
                At[(size_t)n*2048 + 1024 + col] = v;
            }
}

// ===========================================================================
// Stage 4: extractor GEMM (R8-verified, K=2048) + bias + tanh -> f32 hv/tv
// ===========================================================================
__global__ __launch_bounds__(256) void gemm_ext_mfma(
    const unsigned short* __restrict__ Ah, const unsigned short* __restrict__ At,
    const unsigned short* __restrict__ WhT, const unsigned short* __restrict__ WtT,
    const float* __restrict__ bh, const float* __restrict__ bt,
    float* __restrict__ hv, float* __restrict__ tv)
{
    int z = blockIdx.z;
    const unsigned short* A  = z ? At  : Ah;
    const unsigned short* Bt = z ? WtT : WhT;
    const float* bias = z ? bt : bh;
    float* C = z ? tv : hv;
    int row0 = blockIdx.y*128, col0 = blockIdx.x*128;
    f4 acc[4][4] = {};
    gemm128_core(A, Bt, 2048, row0, col0, acc);
    int lane = threadIdx.x & 63, wave = threadIdx.x >> 6;
    int wr = wave & 1, wc = wave >> 1, lm = lane & 15, quad = lane >> 4;
    #pragma unroll
    for (int ti = 0; ti < 4; ++ti)
        #pragma unroll
        for (int tj = 0; tj < 4; ++tj)
            #pragma unroll
            for (int r = 0; r < 4; ++r) {
                int row = row0 + wr*64 + ti*16 + quad*4 + r;
                int col = col0 + wc*64 + tj*16 + lm;
                float x = acc[ti][tj][r] + bias[col];
                float e = __expf(2.f*x);
                C[(size_t)row*D_ + col] = 1.f - 2.f/(e + 1.f);   // tanh
            }
}

// ===========================================================================
// Stage 5a: init output with bias
// ===========================================================================
__global__ void out_init(const float* __restrict__ bb, float* __restrict__ out)
{
    int i = blockIdx.x*256 + threadIdx.x;
    if (i < NROW*C_) out[i] = bb[i % C_];
}

// ===========================================================================
// Stage 5b: block-bilinear classifier — R8-VERIFIED 64-row kernel, verbatim
// numeric path. ONLY change: grid dims swapped to (kb=x:12, rowtile=y:64) so
// dispatch ord = kb + 12*rowtile -> XCD=(kb+4*rowtile)%8 pins each 1MB kb
// slice of WbT to 2 XCDs (3MB/XCD L2 working set, fits 4MB) instead of all
// XCDs streaming all 12MB (L2 thrash).
// ===========================================================================
__global__ __launch_bounds__(256) void final_mfma(
    const float* __restrict__ hv,             // [4096][768] f32
    const float* __restrict__ tv,
    const unsigned short* __restrict__ WbT,   // [12][64][128][64] bf16
    float* __restrict__ out)                  // [4096][97] f32
{
    int kb   = blockIdx.x;        // <- swapped
    int row0 = blockIdx.y * 64;   // <- swapped
    __shared__ __attribute__((aligned(16))) unsigned short hS[64][72];
    __shared__ __attribute__((aligned(16))) unsigned short tS[64][72];
    __shared__ __attribute__((aligned(16))) unsigned short Ws[2][128*64];

    int tid = threadIdx.x;
    // stage hv/tv kb-slices (64 rows x 64), f32 -> bf16 on the fly
    for (int e = tid; e < 1024; e += 256) {
        int r = e >> 4, part = e & 15;
        float4 xh = *(const float4*)(hv + (size_t)(row0 + r)*D_ + kb*BLK_ + part*4);
        float4 xt = *(const float4*)(tv + (size_t)(row0 + r)*D_ + kb*BLK_ + part*4);
        ushort4v ph = { f2bf(xh.x), f2bf(xh.y), f2bf(xh.z), f2bf(xh.w) };
        ushort4v pt = { f2bf(xt.x), f2bf(xt.y), f2bf(xt.z), f2bf(xt.w) };
        *(ushort4v*)&hS[r][part*4] = ph;
        *(ushort4v*)&tS[r][part*4] = pt;
    }
    int wave = tid >> 6, lane = tid & 63;
    int wr = wave & 1, wc = wave >> 1;
    int lm = lane & 15, quad = lane >> 4;
    __syncthreads();

    // preload tv fragments as scalar f32 (i-invariant within this kb)
    float tvv[2][2][8];   // [rowtile][jhalf][t]
    #pragma unroll
    for (int rt = 0; rt < 2; ++rt)
        #pragma unroll
        for (int j2 = 0; j2 < 2; ++j2) {
            int r = wr*32 + rt*16 + lm;
            ushort8 w = *(const ushort8*)&tS[r][j2*32 + quad*8];
            #pragma unroll
            for (int t = 0; t < 8; ++t) tvv[rt][j2][t] = bf2f(w[t]);
        }

    f4 acc[2][4] = {};
    const unsigned short* wbase = WbT + (size_t)kb*64*128*64;

    // precompute per-thread staging indices (R8-verified mapping)
    int swz_off[8];
    #pragma unroll
    for (int s = 0; s < 8; ++s) {
        int ch = tid + s*256;
        int ip = ch >> 10, rem = ch & 1023, c = rem >> 3, g = rem & 7;
        swz_off[s] = ip*(128*64) + c*64 + ((g ^ (c & 7))*8);
    }

    for (int i0 = 0; i0 < 64; i0 += 2) {
        // 8 independent loads first — latency overlaps previous iter's MFMAs
        ushort8 vbuf[8];
        #pragma unroll
        for (int s = 0; s < 8; ++s) {
            int ch = tid + s*256;
            int ip = ch >> 10, rem = ch & 1023, c = rem >> 3, g = rem & 7;
            vbuf[s] = *(const ushort8*)(wbase + (size_t)((i0 + ip)*128 + c)*64 + g*8);
        }
        __syncthreads();   // previous iteration's compute done; Ws reusable
        #pragma unroll
        for (int s = 0; s < 8; ++s)
            *(ushort8*)&Ws[0][swz_off[s]] = vbuf[s];
        __syncthreads();

        #pragma unroll
        for (int ip = 0; ip < 2; ++ip) {
            int i = i0 + ip;
            float sh0 = bf2f(hS[wr*32 + lm][i]);
            float sh1 = bf2f(hS[wr*32 + 16 + lm][i]);
            #pragma unroll
            for (int j2 = 0; j2 < 2; ++j2) {
                // build A-frags: bf16-truncate(sh * tvv) packed via v_perm
                s8 afr[2];
                #pragma unroll
                for (int rt = 0; rt < 2; ++rt) {
                    float sh = rt ? sh1 : sh0;
                    union { unsigned u[4]; s8 v; } cv;
                    #pragma unroll
                    for (int t2 = 0; t2 < 4; ++t2) {
                        float pe = sh * tvv[rt][j2][t2*2];
                        float po = sh * tvv[rt][j2][t2*2 + 1];
                        cv.u[t2] = __builtin_amdgcn_perm(__builtin_bit_cast(unsigned, po),
                                                         __builtin_bit_cast(unsigned, pe),
                                                         0x07060302u);
                    }
                    afr[rt] = cv.v;
                }
                #pragma unroll
                for (int ct = 0; ct < 4; ++ct) {
                    int c = wc*64 + ct*16 + lm;
                    int g = j2*4 + quad;
                    s8 bfr = *(const s8*)&Ws[ip][c*64 + ((g ^ (c & 7))*8)];
                    acc[0][ct] = __builtin_amdgcn_mfma_f32_16x16x32_bf16(afr[0], bfr, acc[0][ct], 0, 0, 0);
                    acc[1][ct] = __builtin_amdgcn_mfma_f32_16x16x32_bf16(afr[1], bfr, acc[1][ct], 0, 0, 0);
                }
            }
        }
    }

    #pragma unroll
    for (int rt = 0; rt < 2; ++rt)
        #pragma unroll
        for (int ct = 0; ct < 4; ++ct)
            #pragma unroll
            for (int r = 0; r < 4; ++r) {
                int row = row0 + wr*32 + rt*16 + quad*4 + r;
                int col = wc*64 + ct*16 + lm;
                if (col < C_) atomicAdd(out + (size_t)row*C_ + col, acc[rt][ct][r]);
            }
}

// ===========================================================================
extern "C" void kernel_launch(void* const* d_in, const int* in_sizes, int n_in,
                              void* d_out, int out_size, void* d_ws, size_t ws_size,
                              hipStream_t stream)
{
    const float* seq_lhs = (const float*)d_in[0];
    const float* ent_lhs = (const float*)d_in[1];
    const float* attn    = (const float*)d_in[2];
    const int*   labels  = (const int*)d_in[3];
    const int*   hts     = (const int*)d_in[4];
    const float* Wh      = (const float*)d_in[5];
    const float* bh      = (const float*)d_in[6];
    const float* Wt      = (const float*)d_in[7];
    const float* bt      = (const float*)d_in[8];
    const float* Wb      = (const float*)d_in[9];
    const float* bb      = (const float*)d_in[10];
    float* out = (float*)d_out;

    float* wsf      = (float*)d_ws;
    float* hv       = wsf;                       // 3145728 f32
    float* tv       = hv + 3145728;              // 3145728 f32
    unsigned short* ent_embB  = (unsigned short*)(tv + 3145728); // 262144
    unsigned short* ent_attnB = ent_embB  + 262144;   // 2097152
    unsigned short* htA       = ent_attnB + 2097152;  // 2097152
    unsigned short* seqT      = htA       + 2097152;  // 2097152
    unsigned short* WhT       = seqT      + 2097152;  // 1572864
    unsigned short* WtT       = WhT       + 1572864;  // 1572864
    unsigned short* Ah        = WtT       + 1572864;  // 8388608 ([4096][2048])
    unsigned short* At        = Ah        + 8388608;  // 8388608
    unsigned short* WbT       = At        + 8388608;  // 6291456
    // total ~90.4 MB

    // weight preps (independent of activations)
    transpose_cvt_W<<<dim3(24, 64, 2), 256, 0, stream>>>(Wh, Wt, WhT, WtT);
    prep_WbT<<<KB_*64, 256, 0, stream>>>(Wb, WbT);
    transpose_cvt_seq<<<dim3(32, 16, B_), 256, 0, stream>>>(seq_lhs, seqT);

    pool_lse<<<B_*E_, 256, 0, stream>>>(ent_lhs, labels, ent_embB);
    pool_attn<<<dim3(E_, B_*NH_), 256, 0, stream>>>(attn, labels, ent_attnB);
    pair_attn_kernel<<<B_*R_, 256, 0, stream>>>(ent_attnB, hts, htA);
    gemm_rel_mfma<<<dim3(8, 8, B_), 256, 0, stream>>>(htA, seqT, Ah, At);
    prep_gather<<<NROW, 256, 0, stream>>>(ent_embB, hts, Ah, At);
    gemm_ext_mfma<<<dim3(6, 32, 2), 256, 0, stream>>>(Ah, At, WhT, WtT, bh, bt, hv, tv);
    out_init<<<(NROW*C_ + 255)/256, 256, 0, stream>>>(bb, out);
    final_mfma<<<dim3(KB_, NROW/64), 256, 0, stream>>>(hv, tv, WbT, out);
}